// Round 2
// baseline (629.265 us; speedup 1.0000x reference)
//
#include <hip/hip_runtime.h>

#define N_NODES 100000
#define F_IN 512
#define HID 16
#define F_OUT 40

// ws layout (float offsets):
//   dinv : [0,          100000)     deg computed here, rsqrt'd in place
//   Hp   : [100000,     3300000)    [N][2][16] K-split partials of x@W1
//   agg1 : [3300000,    4900000)    [N][16]
//   h1   : [4900000,    6500000)    [N][16]
//   agg2 : aliases Hp   [N][16]     (Hp dead after epi1)

// ---------------- init: deg=1 (self-loop), agg1=0 ----------------

__global__ __launch_bounds__(256) void k_init(float* __restrict__ deg,
                                              float* __restrict__ agg1) {
    int i = blockIdx.x * blockDim.x + threadIdx.x;
    if (i < N_NODES) deg[i] = 1.0f;
    if (i < N_NODES * HID) agg1[i] = 0.0f;
}

__global__ void k_deg(const int* __restrict__ ei, int E, float* __restrict__ deg) {
    int stride = gridDim.x * blockDim.x;
    for (int e = blockIdx.x * blockDim.x + threadIdx.x; e < E; e += stride)
        atomicAdd(&deg[ei[e]], 1.0f);
}

__global__ void k_dinv(float* __restrict__ deg) {
    int i = blockIdx.x * blockDim.x + threadIdx.x;
    if (i < N_NODES) deg[i] = rsqrtf(deg[i]);   // deg >= 1 always
}

// ---------------- GEMM1: H = x @ W1, 2-way K-split ----------------

__global__ __launch_bounds__(256) void k_gemm1(const float* __restrict__ x,
                                               const float* __restrict__ W1,
                                               float* __restrict__ Hp, int nb1) {
    int half = (blockIdx.x >= nb1) ? 1 : 0;          // block-uniform -> W idx wave-uniform
    int r = (blockIdx.x - half * nb1) * 256 + threadIdx.x;
    if (r >= N_NODES) return;
    const float* xp = x + (size_t)r * F_IN + half * 256;
    const float* wp = W1 + (size_t)half * 256 * HID;

    float acc[HID];
#pragma unroll
    for (int f = 0; f < HID; ++f) acc[f] = 0.0f;

    for (int k = 0; k < 256; k += 8) {
        float4 a = *reinterpret_cast<const float4*>(xp + k);
        float4 b = *reinterpret_cast<const float4*>(xp + k + 4);
        float xs[8] = {a.x, a.y, a.z, a.w, b.x, b.y, b.z, b.w};
#pragma unroll
        for (int kk = 0; kk < 8; ++kk) {
            float xv = xs[kk];
#pragma unroll
            for (int f = 0; f < HID; ++f)
                acc[f] = fmaf(xv, wp[(k + kk) * HID + f], acc[f]);  // uniform -> s_load
        }
    }
    float* o = Hp + (size_t)r * (2 * HID) + half * HID;
#pragma unroll
    for (int f4 = 0; f4 < 4; ++f4)
        *reinterpret_cast<float4*>(o + f4 * 4) =
            make_float4(acc[f4 * 4 + 0], acc[f4 * 4 + 1], acc[f4 * 4 + 2], acc[f4 * 4 + 3]);
}

// ---------------- edge aggregation: agg[row] += H[col] * norm ----------------
// DUAL=true: H is the [N][2][16] partial buffer (layer 1); else [N][16].

template <bool DUAL>
__global__ __launch_bounds__(256) void k_agg(const int* __restrict__ ei, int E,
                                             const float* __restrict__ dinv,
                                             const float* __restrict__ H,
                                             float* __restrict__ out) {
    long long total = (long long)E * HID;
    long long stride = (long long)gridDim.x * blockDim.x;
    for (long long idx = (long long)blockIdx.x * blockDim.x + threadIdx.x; idx < total;
         idx += stride) {
        int e = (int)(idx >> 4);
        int f = (int)(idx & 15);
        int r = ei[e];
        int c = ei[E + e];
        float nrm = dinv[r] * dinv[c];
        float hv;
        if (DUAL)
            hv = H[(size_t)c * 32 + f] + H[(size_t)c * 32 + 16 + f];
        else
            hv = H[(size_t)c * 16 + f];
        atomicAdd(&out[(size_t)r * HID + f], hv * nrm);
    }
}

// ---------------- epilogue 1: h1 = relu(agg1 + dinv^2 * H + b1); agg2 = 0 ----

__global__ __launch_bounds__(256) void k_epi1(const float* __restrict__ agg1,
                                              const float* __restrict__ Hp,
                                              const float* __restrict__ dinv,
                                              const float* __restrict__ b1,
                                              float* __restrict__ h1,
                                              float* __restrict__ agg2) {
    int idx = blockIdx.x * blockDim.x + threadIdx.x;
    if (idx >= N_NODES * HID) return;
    int i = idx >> 4;
    int f = idx & 15;
    float d = dinv[i];
    float self = Hp[(size_t)i * 32 + f] + Hp[(size_t)i * 32 + 16 + f];
    float v = agg1[idx] + d * d * self + b1[f];
    h1[idx] = fmaxf(v, 0.0f);
    agg2[idx] = 0.0f;     // agg2 aliases Hp region; zeroed here for k_agg<false>
}

// ---------------- epilogue 2: out = (agg2 + dinv^2*h1) @ W2 + b2 ----------------

__global__ __launch_bounds__(256) void k_epi2(const float* __restrict__ agg2,
                                              const float* __restrict__ h1,
                                              const float* __restrict__ dinv,
                                              const float* __restrict__ W2,
                                              const float* __restrict__ b2,
                                              float* __restrict__ out) {
    int r = blockIdx.x * blockDim.x + threadIdx.x;
    if (r >= N_NODES) return;
    float d = dinv[r];
    float d2 = d * d;
    float v[HID];
#pragma unroll
    for (int k4 = 0; k4 < 4; ++k4) {
        float4 a = *reinterpret_cast<const float4*>(agg2 + (size_t)r * HID + k4 * 4);
        float4 h = *reinterpret_cast<const float4*>(h1 + (size_t)r * HID + k4 * 4);
        v[k4 * 4 + 0] = a.x + d2 * h.x;
        v[k4 * 4 + 1] = a.y + d2 * h.y;
        v[k4 * 4 + 2] = a.z + d2 * h.z;
        v[k4 * 4 + 3] = a.w + d2 * h.w;
    }
    float o[F_OUT];
#pragma unroll
    for (int f = 0; f < F_OUT; ++f) o[f] = b2[f];   // uniform -> s_load
#pragma unroll
    for (int k = 0; k < HID; ++k) {
        float vk = v[k];
#pragma unroll
        for (int f = 0; f < F_OUT; ++f)
            o[f] = fmaf(vk, W2[k * F_OUT + f], o[f]);  // uniform -> s_load
    }
#pragma unroll
    for (int f4 = 0; f4 < 10; ++f4)
        *reinterpret_cast<float4*>(out + (size_t)r * F_OUT + f4 * 4) =
            make_float4(o[f4 * 4 + 0], o[f4 * 4 + 1], o[f4 * 4 + 2], o[f4 * 4 + 3]);
}

// ---------------- launch ----------------

extern "C" void kernel_launch(void* const* d_in, const int* in_sizes, int n_in,
                              void* d_out, int out_size, void* d_ws, size_t ws_size,
                              hipStream_t stream) {
    const float* x  = (const float*)d_in[0];
    const int* ei   = (const int*)d_in[1];      // int32: [2][E] row-major
    const float* W1 = (const float*)d_in[2];
    const float* b1 = (const float*)d_in[3];
    const float* W2 = (const float*)d_in[4];
    const float* b2 = (const float*)d_in[5];
    float* out = (float*)d_out;
    const int E = in_sizes[1] / 2;

    float* ws = (float*)d_ws;
    float* dinv = ws;                       // N (deg -> dinv in place)
    float* Hp   = ws + 100000;              // N*32
    float* agg1 = ws + 3300000;             // N*16
    float* h1   = ws + 4900000;             // N*16
    float* agg2 = Hp;                       // alias: Hp dead after k_epi1

    const int nbN  = (N_NODES + 255) / 256;             // 391
    const int nbNF = (N_NODES * HID + 255) / 256;       // 6250

    k_init<<<nbNF, 256, 0, stream>>>(dinv, agg1);
    k_deg<<<1024, 256, 0, stream>>>(ei, E, dinv);
    k_dinv<<<nbN, 256, 0, stream>>>(dinv);

    k_gemm1<<<2 * nbN, 256, 0, stream>>>(x, W1, Hp, nbN);

    k_agg<true><<<2048, 256, 0, stream>>>(ei, E, dinv, Hp, agg1);
    k_epi1<<<nbNF, 256, 0, stream>>>(agg1, Hp, dinv, b1, h1, agg2);
    k_agg<false><<<2048, 256, 0, stream>>>(ei, E, dinv, h1, agg2);
    k_epi2<<<nbN, 256, 0, stream>>>(agg2, h1, dinv, W2, b2, out);
}